// Round 6
// baseline (106.314 us; speedup 1.0000x reference)
//
#include <hip/hip_runtime.h>
#include <hip/hip_bf16.h>

#define BB   16
#define EMB  768
#define CIN  64
#define COUT 64
#define HH   112
#define WW   112
#define HID  192
#define TOTAL 36864                 // COUT*CIN*9
#define KSZ  576                    // CIN*9
#define PW   114                    // padded H/W
#define ROWB (PW * 64 * 2)          // 14592 B: one padded row, NHWC bf16

typedef short bf16x8 __attribute__((ext_vector_type(8)));
typedef float f32x4  __attribute__((ext_vector_type(4)));
typedef int   i32x4  __attribute__((ext_vector_type(4)));

static __device__ __forceinline__ unsigned short f2bf(float f) {
    unsigned u = __float_as_uint(f);
    u += 0x7FFF + ((u >> 16) & 1);          // RNE
    return (unsigned short)(u >> 16);
}

#define GLOAD_LDS16(g, l) \
    __builtin_amdgcn_global_load_lds((const __attribute__((address_space(1))) void*)(g), \
                                     (__attribute__((address_space(3))) void*)(l), 16, 0, 0)

// ---- K1: prepass (blocks 0..1823) + mlp1 (blocks 1824..1871), independent work ----
// prepass: feat NCHW fp32 -> zero-padded NHWC bf16 P[b][py][px][64]
// mlp1:    h = relu(cls @ W1 + b1), 3 blocks per b (64 j each), k-split 4, unroll 48
__global__ __launch_bounds__(256) void fused_pre_mlp1(const float* __restrict__ feat,
                                                      unsigned short* __restrict__ P,
                                                      const float* __restrict__ cls,
                                                      const float* __restrict__ W1,
                                                      const float* __restrict__ b1,
                                                      float* __restrict__ h) {
    __shared__ __align__(16) char smem[WW * 72 * 2];     // 16128 B (prepass ts)
    const int tid = threadIdx.x;

    if (blockIdx.x < PW * BB) {
        // ---------------- prepass ----------------
        unsigned short* ts = (unsigned short*)smem;      // [x][ci], stride 72 el
        const int b  = blockIdx.x & 15;
        const int py = blockIdx.x >> 4;                  // 0..113
        unsigned short* Prow = P + ((size_t)b * PW + py) * (PW * 64);

        if (py == 0 || py == PW - 1) {                   // zero full halo row
            i32x4 z = {0, 0, 0, 0};
            for (int i = tid; i < ROWB / 16; i += 256) ((i32x4*)Prow)[i] = z;
            return;
        }
        const int y = py - 1;
        if (tid < 8)       ((i32x4*)Prow)[tid] = (i32x4){0, 0, 0, 0};
        else if (tid < 16) ((i32x4*)(Prow + (size_t)(PW - 1) * 64))[tid - 8] = (i32x4){0, 0, 0, 0};

        const float* fb = feat + (size_t)b * CIN * HH * WW + (size_t)y * WW;
        #pragma unroll
        for (int it = 0; it < 14; ++it) {
            const int i = it * 256 + tid;                // 0..3583 = 32 ci-pairs x 112 x
            const int p = i / WW;
            const int x = i - p * WW;
            const float va = fb[(size_t)(2 * p) * HH * WW + x];
            const float vb = fb[(size_t)(2 * p + 1) * HH * WW + x];
            const unsigned pk = (unsigned)f2bf(va) | ((unsigned)f2bf(vb) << 16);
            *(unsigned*)(ts + (size_t)x * 72 + 2 * p) = pk;
        }
        __syncthreads();
        for (int j = tid; j < WW * 8; j += 256) {
            const int x = j >> 3, g = j & 7;
            *(bf16x8*)(Prow + (size_t)(x + 1) * 64 + g * 8) = *(const bf16x8*)(ts + x * 72 + g * 8);
        }
    } else {
        // ---------------- mlp1 ----------------
        float* xs  = (float*)smem;                       // 768 floats
        float* red = xs + EMB;                           // 3*64 floats
        const int idx = blockIdx.x - PW * BB;            // 0..47
        const int b   = idx / 3;
        const int jg  = idx - 3 * b;
        for (int i = tid; i < EMB; i += 256) xs[i] = cls[b * EMB + i];
        __syncthreads();
        const int ln = tid & 63;
        const int j  = jg * 64 + ln;
        const int kq = tid >> 6;
        float acc = 0.f;
        #pragma unroll 48
        for (int k = kq * 192; k < kq * 192 + 192; ++k) acc += xs[k] * W1[k * HID + j];
        if (kq) red[(kq - 1) * 64 + ln] = acc;
        __syncthreads();
        if (kq == 0)
            h[b * HID + j] = fmaxf(acc + red[ln] + red[64 + ln] + red[128 + ln] + b1[j], 0.f);
    }
}

// ---- K2: params = tanh(h @ W2 + b2) (+ identity at center tap),
//      written bf16 as A[b][p9][co][ci].  Grid 576 x 256thr, 4 b per thread. ----
__global__ __launch_bounds__(256) void mlp2_kernel(const float* __restrict__ h,
                                                   const float* __restrict__ W2,
                                                   const float* __restrict__ b2,
                                                   unsigned short* __restrict__ Ag) {
    __shared__ float hs[BB * HID];
    const int tid = threadIdx.x;
    for (int i = tid; i < BB * HID; i += 256) hs[i] = h[i];
    __syncthreads();
    const int t  = blockIdx.x * 64 + (tid & 63);   // 0..36863
    const int bq = tid >> 6;                        // b-quarter
    float acc[4];
    const float bias = b2[t];
    #pragma unroll
    for (int q = 0; q < 4; ++q) acc[q] = bias;
    const float* hb = hs + bq * 4 * HID;
    #pragma unroll 24
    for (int k = 0; k < HID; ++k) {
        const float w = W2[(size_t)k * TOTAL + t];
        #pragma unroll
        for (int q = 0; q < 4; ++q) acc[q] += hb[q * HID + k] * w;
    }
    // t = co*576 + ci*9 + p9 ; fold residual: A[center] += I
    const int co  = t / KSZ;
    const int rem = t - co * KSZ;
    const int ci  = rem / 9;
    const int p9  = rem - ci * 9;
    const float idv = (p9 == 4 && co == ci) ? 1.f : 0.f;
    #pragma unroll
    for (int q = 0; q < 4; ++q) {
        const int b = bq * 4 + q;
        Ag[(((size_t)b * 9 + p9) * 64 + co) * 64 + ci] = f2bf(tanhf(acc[q]) + idv);
    }
}

// -------- K3: conv MFMA implicit GEMM, LDS-staged B, identity-fused residual --------
// Block: 256 thr / 4 waves; wave = (co-half, out-row).  Block: 64 co x 2 rows x 112 px.
// LDS: 4 padded rows [s][col][64ci], chunk-XOR swizzle g' = g ^ (col&7).
__global__ __launch_bounds__(256) void conv_kernel(const unsigned short* __restrict__ Ag,
                                                   const unsigned short* __restrict__ P,
                                                   float* __restrict__ out) {
    __shared__ __align__(16) char lds[4 * ROWB];    // 58368 B
    const int tid = threadIdx.x;
    // XCD-chunked swizzle: each XCD owns 112 consecutive logical blocks (= 2 batches)
    const int bid  = (blockIdx.x & 7) * 112 + (blockIdx.x >> 3);
    const int b    = bid / 56;
    const int tile = bid - b * 56;
    const int y0   = tile * 2;
    const int wave = tid >> 6;
    const int lane = tid & 63;
    const int cog  = wave & 1;                      // co half (32 co)
    const int r    = wave >> 1;                     // output row 0/1
    const int lg   = lane >> 4;
    const int ln   = lane & 15;

    // stage padded rows y0..y0+3 via global_load_lds, inverse-swizzled source
    const char* Prow0 = (const char*)(P + ((size_t)b * PW + y0) * (PW * 64));
    #pragma unroll
    for (int it = 0; it < 14; ++it) {
        const int i = it * 256 + tid;               // chunk 0..3583
        const int s = i / 912;
        const int j = i - s * 912;
        const int c = j >> 3, g = j & 7;
        GLOAD_LDS16(Prow0 + (size_t)s * ROWB + c * 128 + ((g ^ (c & 7)) << 4),
                    lds + (size_t)i * 16);
    }
    if (tid < 64) {                                 // chunks 3584..3647
        const int i = 3584 + tid;
        const int j = i - 3 * 912;
        const int c = j >> 3, g = j & 7;
        GLOAD_LDS16(Prow0 + (size_t)3 * ROWB + c * 128 + ((g ^ (c & 7)) << 4),
                    lds + (size_t)i * 16);
    }

    // A-fragments for this wave's 32 co x 9 taps x 64 ci, fully preloaded
    const unsigned short* Ab = Ag + (size_t)b * 9 * 4096;
    bf16x8 af[9][2][2];
    #pragma unroll
    for (int p9 = 0; p9 < 9; ++p9)
        #pragma unroll
        for (int ct = 0; ct < 2; ++ct)
            #pragma unroll
            for (int cib = 0; cib < 2; ++cib)
                af[p9][ct][cib] = *(const bf16x8*)(Ab + (size_t)(p9 * 64 + cog * 32 + ct * 16 + ln) * 64
                                                   + cib * 32 + lg * 8);
    __syncthreads();

    f32x4 acc[2][7];
    #pragma unroll
    for (int ct = 0; ct < 2; ++ct)
        #pragma unroll
        for (int t = 0; t < 7; ++t) acc[ct][t] = (f32x4){0.f, 0.f, 0.f, 0.f};

    #pragma unroll
    for (int p9 = 0; p9 < 9; ++p9) {
        const int kh = p9 / 3, kw = p9 - 3 * kh;
        const char* lbase = lds + (r + kh) * ROWB + (ln + kw) * 128;
        const int   c7    = (ln + kw) & 7;
        #pragma unroll
        for (int cib = 0; cib < 2; ++cib) {
            const int sw = ((cib * 4 + lg) ^ c7) << 4;
            #pragma unroll
            for (int t = 0; t < 7; ++t) {
                const bf16x8 bf = *(const bf16x8*)(lbase + t * 2048 + sw);
                acc[0][t] = __builtin_amdgcn_mfma_f32_16x16x32_bf16(af[p9][0][cib], bf, acc[0][t], 0, 0, 0);
                acc[1][t] = __builtin_amdgcn_mfma_f32_16x16x32_bf16(af[p9][1][cib], bf, acc[1][t], 0, 0, 0);
            }
        }
    }

    // epilogue: pure stores (residual folded into A)
    const int y = y0 + r;
    float* ob = out + (((size_t)b * COUT + cog * 32 + lg * 4) * HH + y) * WW + ln;
    #pragma unroll
    for (int ct = 0; ct < 2; ++ct)
        #pragma unroll
        for (int t = 0; t < 7; ++t)
            #pragma unroll
            for (int rg = 0; rg < 4; ++rg)
                ob[((size_t)(ct * 16 + rg)) * HH * WW + t * 16] = acc[ct][t][rg];
}

extern "C" void kernel_launch(void* const* d_in, const int* in_sizes, int n_in,
                              void* d_out, int out_size, void* d_ws, size_t ws_size,
                              hipStream_t stream) {
    const float* cls      = (const float*)d_in[0];
    const float* features = (const float*)d_in[1];
    const float* W1       = (const float*)d_in[2];
    const float* b1       = (const float*)d_in[3];
    const float* W2       = (const float*)d_in[4];
    const float* b2       = (const float*)d_in[5];
    float* out = (float*)d_out;

    float*          h  = (float*)d_ws;                       // 12 KB
    unsigned short* Ag = (unsigned short*)(h + BB * HID);    // 1.18 MB
    unsigned short* P  = Ag + (size_t)BB * 9 * 4096;         // 26.6 MB padded NHWC bf16

    fused_pre_mlp1<<<PW * BB + 48, 256, 0, stream>>>(features, P, cls, W1, b1, h);
    mlp2_kernel<<<TOTAL / 64, 256, 0, stream>>>(h, W2, b2, Ag);
    conv_kernel<<<56 * BB, 256, 0, stream>>>(Ag, P, out);
}

// Round 7
// 90.837 us; speedup vs baseline: 1.1704x; 1.1704x over previous
//
#include <hip/hip_runtime.h>
#include <hip/hip_bf16.h>

#define BB   16
#define EMB  768
#define CIN  64
#define COUT 64
#define HH   112
#define WW   112
#define HID  192
#define TOTAL 36864                 // COUT*CIN*9
#define KSZ  576                    // CIN*9
#define SCOLS 114                   // padded cols (-1..112)
#define CELL  128                   // bytes per (row,col) cell: 64 ci * 2B
#define ROWB (SCOLS * CELL)         // 14592 B per padded row

typedef short bf16x8 __attribute__((ext_vector_type(8)));
typedef float f32x4  __attribute__((ext_vector_type(4)));
typedef int   i32x4  __attribute__((ext_vector_type(4)));

static __device__ __forceinline__ unsigned short f2bf(float f) {
    unsigned u = __float_as_uint(f);
    u += 0x7FFF + ((u >> 16) & 1);          // RNE
    return (unsigned short)(u >> 16);
}

// ---- K1: h = relu(cls @ W1 + b1).  192 blocks = 16b x 12jg; 256 thr = 16j x 16kq ----
__global__ __launch_bounds__(256) void mlp1_kernel(const float* __restrict__ cls,
                                                   const float* __restrict__ W1,
                                                   const float* __restrict__ b1,
                                                   float* __restrict__ h) {
    __shared__ float xs[EMB];
    __shared__ float red[16][17];
    const int b   = blockIdx.x / 12;
    const int jg  = blockIdx.x - 12 * b;
    const int tid = threadIdx.x;
    for (int i = tid; i < EMB; i += 256) xs[i] = cls[b * EMB + i];
    __syncthreads();
    const int j16 = tid & 15;
    const int kq  = tid >> 4;
    const int j   = jg * 16 + j16;
    float acc = 0.f;
    #pragma unroll
    for (int k = kq * 48; k < kq * 48 + 48; ++k) acc += xs[k] * W1[k * HID + j];
    red[j16][kq] = acc;
    __syncthreads();
    if (tid < 16) {
        float s = b1[jg * 16 + tid];
        #pragma unroll
        for (int q = 0; q < 16; ++q) s += red[tid][q];
        h[b * HID + jg * 16 + tid] = fmaxf(s, 0.f);
    }
}

// ---- K2: params = tanh(h @ W2 + b2) (+ identity at center tap),
//      bf16 out as A[b][p9][co][ci].  144 blocks; thread = 4t x 4b, float4 W2. ----
__global__ __launch_bounds__(256) void mlp2_kernel(const float* __restrict__ h,
                                                   const float* __restrict__ W2,
                                                   const float* __restrict__ b2,
                                                   unsigned short* __restrict__ Ag) {
    __shared__ float hs[BB * HID];
    const int tid = threadIdx.x;
    for (int i = tid; i < BB * HID; i += 256) hs[i] = h[i];
    __syncthreads();
    const int tq = tid & 63;
    const int bq = tid >> 6;
    const int t0 = blockIdx.x * 256 + tq * 4;
    f32x4 acc[4];
    const f32x4 bias = *(const f32x4*)(b2 + t0);
    #pragma unroll
    for (int q = 0; q < 4; ++q) acc[q] = bias;
    const float* hb = hs + bq * 4 * HID;
    #pragma unroll 16
    for (int k = 0; k < HID; ++k) {
        const f32x4 w = *(const f32x4*)(W2 + (size_t)k * TOTAL + t0);
        #pragma unroll
        for (int q = 0; q < 4; ++q) acc[q] += hb[q * HID + k] * w;
    }
    #pragma unroll
    for (int q = 0; q < 4; ++q) {
        const int b = bq * 4 + q;
        #pragma unroll
        for (int j = 0; j < 4; ++j) {
            const int t   = t0 + j;
            const int co  = t / KSZ;
            const int rem = t - co * KSZ;
            const int ci  = rem / 9;
            const int p9  = rem - ci * 9;
            const float idv = (p9 == 4 && co == ci) ? 1.f : 0.f;
            Ag[(((size_t)b * 9 + p9) * 64 + co) * 64 + ci] = f2bf(tanhf(acc[q][j]) + idv);
        }
    }
}

// -------- K3: conv MFMA implicit GEMM with in-block fp32->bf16 NHWC transpose --------
// Block: 256 thr / 4 waves; wave = (co-half, out-row). Block: 64 co x 2 rows x 112 px.
// LDS: 4 padded rows [r][cell 0..113][64ci], slice swizzle sl = (ci>>3) ^ (cell&7).
// Staging: thread = (ci-octet o = tid>>5, row r = (tid>>3)&3, xg = tid&7 -> 14 px);
// per px: pack 8 ci -> one ds_write_b128 (slice spread -> conflict-free).
__global__ __launch_bounds__(256) void conv_kernel(const float* __restrict__ feat,
                                                   const unsigned short* __restrict__ Ag,
                                                   float* __restrict__ out) {
    __shared__ __align__(16) char lds[4 * ROWB];    // 58368 B
    const int tid = threadIdx.x;
    // XCD-chunked swizzle: each XCD owns 112 consecutive logical blocks (= 2 batches)
    const int bid  = (blockIdx.x & 7) * 112 + (blockIdx.x >> 3);
    const int b    = bid / 56;
    const int tile = bid - b * 56;
    const int y0   = tile * 2;

    // ---- staging: zero x-halo cells (0,113), then transpose-write the tile ----
    if (tid < 64) {
        const int zr = tid >> 4, zc = ((tid >> 3) & 1) ? (SCOLS - 1) : 0, zs = tid & 7;
        *(i32x4*)(lds + (zr * SCOLS + zc) * CELL + zs * 16) = (i32x4){0, 0, 0, 0};
    }
    {
        const int o  = tid >> 5;                    // ci octet 0..7
        const int rr = (tid >> 3) & 3;              // staged row 0..3
        const int xg = tid & 7;                     // 14-px group
        const int y  = y0 - 1 + rr;
        const bool yv = (unsigned)y < HH;
        const float* frow = feat + (((size_t)b * CIN + o * 8) * HH + y) * WW + xg * 14;
        const float2 z2 = {0.f, 0.f};
        char* ldsr = lds + rr * ROWB;

        // half A: px 0..7
        float2 fA[8][4];
        #pragma unroll
        for (int k = 0; k < 8; ++k) {
            const float* rk = frow + (size_t)k * (HH * WW);
            #pragma unroll
            for (int j = 0; j < 4; ++j) fA[k][j] = yv ? *(const float2*)(rk + 2 * j) : z2;
        }
        #pragma unroll
        for (int i = 0; i < 8; ++i) {
            const int cell = xg * 14 + i + 1;
            const int sl   = o ^ (cell & 7);
            const int hi = i >> 1, od = i & 1;
            unsigned v[4];
            #pragma unroll
            for (int kp = 0; kp < 4; ++kp) {
                const float a = od ? fA[2 * kp][hi].y     : fA[2 * kp][hi].x;
                const float c = od ? fA[2 * kp + 1][hi].y : fA[2 * kp + 1][hi].x;
                v[kp] = (unsigned)f2bf(a) | ((unsigned)f2bf(c) << 16);
            }
            *(i32x4*)(ldsr + cell * CELL + sl * 16) =
                (i32x4){(int)v[0], (int)v[1], (int)v[2], (int)v[3]};
        }
        // half B: px 8..13
        float2 fB[8][3];
        #pragma unroll
        for (int k = 0; k < 8; ++k) {
            const float* rk = frow + (size_t)k * (HH * WW) + 8;
            #pragma unroll
            for (int j = 0; j < 3; ++j) fB[k][j] = yv ? *(const float2*)(rk + 2 * j) : z2;
        }
        #pragma unroll
        for (int i = 0; i < 6; ++i) {
            const int cell = xg * 14 + 8 + i + 1;
            const int sl   = o ^ (cell & 7);
            const int hi = i >> 1, od = i & 1;
            unsigned v[4];
            #pragma unroll
            for (int kp = 0; kp < 4; ++kp) {
                const float a = od ? fB[2 * kp][hi].y     : fB[2 * kp][hi].x;
                const float c = od ? fB[2 * kp + 1][hi].y : fB[2 * kp + 1][hi].x;
                v[kp] = (unsigned)f2bf(a) | ((unsigned)f2bf(c) << 16);
            }
            *(i32x4*)(ldsr + cell * CELL + sl * 16) =
                (i32x4){(int)v[0], (int)v[1], (int)v[2], (int)v[3]};
        }
    }

    // ---- A-fragments (issued while staging writes drain) ----
    const int wave = tid >> 6;
    const int lane = tid & 63;
    const int cog  = wave & 1;                      // co half (32 co)
    const int r    = wave >> 1;                     // output row 0/1
    const int lg   = lane >> 4;
    const int ln   = lane & 15;
    const unsigned short* Ab = Ag + (size_t)b * 9 * 4096;
    bf16x8 af[9][2][2];
    #pragma unroll
    for (int p9 = 0; p9 < 9; ++p9)
        #pragma unroll
        for (int ct = 0; ct < 2; ++ct)
            #pragma unroll
            for (int cib = 0; cib < 2; ++cib)
                af[p9][ct][cib] = *(const bf16x8*)(Ab + (size_t)(p9 * 64 + cog * 32 + ct * 16 + ln) * 64
                                                   + cib * 32 + lg * 8);
    __syncthreads();

    f32x4 acc[2][7];
    #pragma unroll
    for (int ct = 0; ct < 2; ++ct)
        #pragma unroll
        for (int t = 0; t < 7; ++t) acc[ct][t] = (f32x4){0.f, 0.f, 0.f, 0.f};

    #pragma unroll
    for (int p9 = 0; p9 < 9; ++p9) {
        const int kh = p9 / 3, kw = p9 - 3 * kh;
        const char* lbase = lds + (r + kh) * ROWB + (ln + kw) * CELL;
        const int   c7    = (ln + kw) & 7;
        #pragma unroll
        for (int cib = 0; cib < 2; ++cib) {
            const int sw = ((cib * 4 + lg) ^ c7) << 4;
            #pragma unroll
            for (int t = 0; t < 7; ++t) {
                const bf16x8 bf = *(const bf16x8*)(lbase + t * 2048 + sw);
                acc[0][t] = __builtin_amdgcn_mfma_f32_16x16x32_bf16(af[p9][0][cib], bf, acc[0][t], 0, 0, 0);
                acc[1][t] = __builtin_amdgcn_mfma_f32_16x16x32_bf16(af[p9][1][cib], bf, acc[1][t], 0, 0, 0);
            }
        }
    }

    // epilogue: pure stores (residual folded into A)
    const int y = y0 + r;
    float* ob = out + (((size_t)b * COUT + cog * 32 + lg * 4) * HH + y) * WW + ln;
    #pragma unroll
    for (int ct = 0; ct < 2; ++ct)
        #pragma unroll
        for (int t = 0; t < 7; ++t)
            #pragma unroll
            for (int rg = 0; rg < 4; ++rg)
                ob[((size_t)(ct * 16 + rg)) * HH * WW + t * 16] = acc[ct][t][rg];
}

extern "C" void kernel_launch(void* const* d_in, const int* in_sizes, int n_in,
                              void* d_out, int out_size, void* d_ws, size_t ws_size,
                              hipStream_t stream) {
    const float* cls      = (const float*)d_in[0];
    const float* features = (const float*)d_in[1];
    const float* W1       = (const float*)d_in[2];
    const float* b1       = (const float*)d_in[3];
    const float* W2       = (const float*)d_in[4];
    const float* b2       = (const float*)d_in[5];
    float* out = (float*)d_out;

    float*          h  = (float*)d_ws;                       // 12 KB
    unsigned short* Ag = (unsigned short*)(h + BB * HID);    // 1.18 MB bf16 A[b][p9][co][ci]

    mlp1_kernel<<<192, 256, 0, stream>>>(cls, W1, b1, h);
    mlp2_kernel<<<TOTAL / 256, 256, 0, stream>>>(h, W2, b2, Ag);
    conv_kernel<<<56 * BB, 256, 0, stream>>>(features, Ag, out);
}

// Round 8
// 58.323 us; speedup vs baseline: 1.8228x; 1.5575x over previous
//
#include <hip/hip_runtime.h>
#include <hip/hip_bf16.h>

#define BB   16
#define EMB  768
#define CIN  64
#define COUT 64
#define HH   112
#define WW   112
#define HID  192
#define TOTAL 36864                 // COUT*CIN*9
#define KSZ  576                    // CIN*9
#define SCOLS 114                   // padded cols (-1..112)
#define CELL  128                   // bytes per (row,col) cell: 64 ci * 2B
#define ROWB (SCOLS * CELL)         // 14592 B per padded row

typedef short bf16x8 __attribute__((ext_vector_type(8)));
typedef float f32x4  __attribute__((ext_vector_type(4)));
typedef int   i32x4  __attribute__((ext_vector_type(4)));

static __device__ __forceinline__ unsigned short f2bf(float f) {
    unsigned u = __float_as_uint(f);
    u += 0x7FFF + ((u >> 16) & 1);          // RNE
    return (unsigned short)(u >> 16);
}

static __device__ __forceinline__ bf16x8 pack8(const float* v) {
    bf16x8 r;
    #pragma unroll
    for (int j = 0; j < 8; ++j) r[j] = (short)f2bf(v[j]);
    return r;
}

// ---- K1: h = relu(cls @ W1 + b1).  192 blocks = 16b x 12jg; 256 thr = 16j x 16kq ----
__global__ __launch_bounds__(256) void mlp1_kernel(const float* __restrict__ cls,
                                                   const float* __restrict__ W1,
                                                   const float* __restrict__ b1,
                                                   float* __restrict__ h) {
    __shared__ float xs[EMB];
    __shared__ float red[16][17];
    const int b   = blockIdx.x / 12;
    const int jg  = blockIdx.x - 12 * b;
    const int tid = threadIdx.x;
    for (int i = tid; i < EMB; i += 256) xs[i] = cls[b * EMB + i];
    __syncthreads();
    const int j16 = tid & 15;
    const int kq  = tid >> 4;
    const int j   = jg * 16 + j16;
    float acc = 0.f;
    #pragma unroll
    for (int k = kq * 48; k < kq * 48 + 48; ++k) acc += xs[k] * W1[k * HID + j];
    red[j16][kq] = acc;
    __syncthreads();
    if (tid < 16) {
        float s = b1[jg * 16 + tid];
        #pragma unroll
        for (int q = 0; q < 16; ++q) s += red[tid][q];
        h[b * HID + jg * 16 + tid] = fmaxf(s, 0.f);
    }
}

// ---- K2: MFMA GEMM  params = tanh(h @ W2 + b2) (+ identity at center tap),
//      bf16 out as A[b][p9][co][ci].  M=16(b), K=192, N=36864.
//      576 blocks x 4 waves; wave = one 16-col n-tile. W2 converted fp32->bf16 in-reg. ----
__global__ __launch_bounds__(256) void mlp2_kernel(const float* __restrict__ h,
                                                   const float* __restrict__ W2,
                                                   const float* __restrict__ b2,
                                                   unsigned short* __restrict__ Ag) {
    __shared__ float hs[16 * 193];              // padded stride vs bank conflicts
    const int tid = threadIdx.x;
    for (int i = tid; i < BB * HID; i += 256) {
        const int bb = i / HID;
        hs[bb * 193 + (i - bb * HID)] = h[i];
    }
    __syncthreads();
    const int wave = tid >> 6;
    const int lane = tid & 63;
    const int lg   = lane >> 4;
    const int ln   = lane & 15;
    const int t0   = (blockIdx.x * 4 + wave) * 16;

    // A-fragments: lane ln = m = batch row, k = kk*32 + lg*8 + j
    bf16x8 a6[6];
    #pragma unroll
    for (int kk = 0; kk < 6; ++kk) {
        float v[8];
        #pragma unroll
        for (int j = 0; j < 8; ++j) v[j] = hs[ln * 193 + kk * 32 + lg * 8 + j];
        a6[kk] = pack8(v);
    }

    // K loop: B-fragment = W2[k][t0+ln], 48 independent coalesced dword loads
    f32x4 acc = (f32x4){0.f, 0.f, 0.f, 0.f};
    #pragma unroll
    for (int kk = 0; kk < 6; ++kk) {
        float w[8];
        #pragma unroll
        for (int j = 0; j < 8; ++j)
            w[j] = W2[(size_t)(kk * 32 + lg * 8 + j) * TOTAL + t0 + ln];
        acc = __builtin_amdgcn_mfma_f32_16x16x32_bf16(a6[kk], pack8(w), acc, 0, 0, 0);
    }

    // epilogue: D row = lg*4+rg = b, col = ln -> t
    const int t    = t0 + ln;
    const float bias = b2[t];
    const int co  = t / KSZ;
    const int rem = t - co * KSZ;
    const int ci  = rem / 9;
    const int p9  = rem - ci * 9;
    const float idv = (p9 == 4 && co == ci) ? 1.f : 0.f;
    unsigned short* pA = Ag + (size_t)(p9 * 64 + co) * 64 + ci;
    #pragma unroll
    for (int rg = 0; rg < 4; ++rg) {
        const int bi = lg * 4 + rg;
        pA[(size_t)bi * TOTAL] = f2bf(tanhf(acc[rg] + bias) + idv);
    }
}

// -------- K3: conv MFMA implicit GEMM with in-block fp32->bf16 NHWC transpose --------
// Block: 256 thr / 4 waves; wave = (co-half, out-row). Block: 64 co x 2 rows x 112 px.
// LDS: 4 padded rows [r][cell 0..113][64ci], slice swizzle sl = (ci>>3) ^ (cell&7) ^ r.
// Staging: thread = (o = ci-octet, rr = row, xs 0..6); loads px-CONTIGUOUS across lanes
// (7 lanes x float4 = 112B runs), writes one ds_write_b128 per px (8 ci packed).
__global__ __launch_bounds__(256) void conv_kernel(const float* __restrict__ feat,
                                                   const unsigned short* __restrict__ Ag,
                                                   float* __restrict__ out) {
    __shared__ __align__(16) char lds[4 * ROWB];    // 58368 B
    const int tid = threadIdx.x;
    // XCD-chunked swizzle: each XCD owns 112 consecutive logical blocks (= 2 batches)
    const int bid  = (blockIdx.x & 7) * 112 + (blockIdx.x >> 3);
    const int b    = bid / 56;
    const int tile = bid - b * 56;
    const int y0   = tile * 2;

    // zero x-halo cells (0, 113) for all 4 rows
    if (tid < 64) {
        const int zr = tid >> 4, zc = ((tid >> 3) & 1) ? (SCOLS - 1) : 0, zs = tid & 7;
        *(i32x4*)(lds + (zr * SCOLS + zc) * CELL + zs * 16) = (i32x4){0, 0, 0, 0};
    }

    // ---- staging ----
    {
        const int o  = tid >> 5;                    // ci octet 0..7
        const int rr = (tid >> 3) & 3;              // staged row 0..3
        const int xs = tid & 7;                     // chunk lane 0..6 (7 idle)
        if (xs < 7) {
            const int y  = y0 - 1 + rr;
            const bool yv = (unsigned)y < HH;
            const float* fp = feat + (((size_t)b * CIN + o * 8) * HH + y) * WW + 4 * xs;
            const f32x4 z4 = {0.f, 0.f, 0.f, 0.f};
            char* ldsr = lds + rr * ROWB;
            #pragma unroll
            for (int sh = 0; sh < 2; ++sh) {
                f32x4 v[8][2];
                #pragma unroll
                for (int ss = 0; ss < 2; ++ss) {
                    const int s = sh * 2 + ss;
                    #pragma unroll
                    for (int j = 0; j < 8; ++j)
                        v[j][ss] = yv ? *(const f32x4*)(fp + (size_t)j * (HH * WW) + s * 28)
                                      : z4;
                }
                #pragma unroll
                for (int ss = 0; ss < 2; ++ss) {
                    const int s = sh * 2 + ss;
                    #pragma unroll
                    for (int j2 = 0; j2 < 4; ++j2) {
                        const int cell = 4 * (s * 7 + xs) + j2 + 1;
                        const int sl   = (o ^ (cell & 7) ^ rr) & 7;
                        const unsigned d0 = (unsigned)f2bf(v[0][ss][j2]) | ((unsigned)f2bf(v[1][ss][j2]) << 16);
                        const unsigned d1 = (unsigned)f2bf(v[2][ss][j2]) | ((unsigned)f2bf(v[3][ss][j2]) << 16);
                        const unsigned d2 = (unsigned)f2bf(v[4][ss][j2]) | ((unsigned)f2bf(v[5][ss][j2]) << 16);
                        const unsigned d3 = (unsigned)f2bf(v[6][ss][j2]) | ((unsigned)f2bf(v[7][ss][j2]) << 16);
                        *(i32x4*)(ldsr + cell * CELL + sl * 16) =
                            (i32x4){(int)d0, (int)d1, (int)d2, (int)d3};
                    }
                }
            }
        }
    }

    // ---- A-fragments: 32 co x 9 taps x 64 ci per wave ----
    const int wave = tid >> 6;
    const int lane = tid & 63;
    const int cog  = wave & 1;                      // co half (32 co)
    const int r    = wave >> 1;                     // output row 0/1
    const int lg   = lane >> 4;
    const int ln   = lane & 15;
    const unsigned short* Ab = Ag + (size_t)b * 9 * 4096;
    bf16x8 af[9][2][2];
    #pragma unroll
    for (int p9 = 0; p9 < 9; ++p9)
        #pragma unroll
        for (int ct = 0; ct < 2; ++ct)
            #pragma unroll
            for (int cib = 0; cib < 2; ++cib)
                af[p9][ct][cib] = *(const bf16x8*)(Ab + (size_t)(p9 * 64 + cog * 32 + ct * 16 + ln) * 64
                                                   + cib * 32 + lg * 8);
    __syncthreads();

    f32x4 acc[2][7];
    #pragma unroll
    for (int ct = 0; ct < 2; ++ct)
        #pragma unroll
        for (int t = 0; t < 7; ++t) acc[ct][t] = (f32x4){0.f, 0.f, 0.f, 0.f};

    #pragma unroll
    for (int p9 = 0; p9 < 9; ++p9) {
        const int kh = p9 / 3, kw = p9 - 3 * kh;
        const int rs = r + kh;
        const char* lbase = lds + rs * ROWB + (ln + kw) * CELL;
        const int   c7    = (ln + kw) & 7;
        #pragma unroll
        for (int cib = 0; cib < 2; ++cib) {
            const int sw = (((cib * 4 + lg) ^ c7 ^ rs) & 7) << 4;
            #pragma unroll
            for (int t = 0; t < 7; ++t) {
                const bf16x8 bf = *(const bf16x8*)(lbase + t * 2048 + sw);
                acc[0][t] = __builtin_amdgcn_mfma_f32_16x16x32_bf16(af[p9][0][cib], bf, acc[0][t], 0, 0, 0);
                acc[1][t] = __builtin_amdgcn_mfma_f32_16x16x32_bf16(af[p9][1][cib], bf, acc[1][t], 0, 0, 0);
            }
        }
    }

    // epilogue: pure stores (residual folded into A)
    const int y = y0 + r;
    float* ob = out + (((size_t)b * COUT + cog * 32 + lg * 4) * HH + y) * WW + ln;
    #pragma unroll
    for (int ct = 0; ct < 2; ++ct)
        #pragma unroll
        for (int t = 0; t < 7; ++t)
            #pragma unroll
            for (int rg = 0; rg < 4; ++rg)
                ob[((size_t)(ct * 16 + rg)) * HH * WW + t * 16] = acc[ct][t][rg];
}

extern "C" void kernel_launch(void* const* d_in, const int* in_sizes, int n_in,
                              void* d_out, int out_size, void* d_ws, size_t ws_size,
                              hipStream_t stream) {
    const float* cls      = (const float*)d_in[0];
    const float* features = (const float*)d_in[1];
    const float* W1       = (const float*)d_in[2];
    const float* b1       = (const float*)d_in[3];
    const float* W2       = (const float*)d_in[4];
    const float* b2       = (const float*)d_in[5];
    float* out = (float*)d_out;

    float*          h  = (float*)d_ws;                       // 12 KB
    unsigned short* Ag = (unsigned short*)(h + BB * HID);    // 1.18 MB bf16 A[b][p9][co][ci]

    mlp1_kernel<<<192, 256, 0, stream>>>(cls, W1, b1, h);
    mlp2_kernel<<<TOTAL / 64, 256, 0, stream>>>(h, W2, b2, Ag);
    conv_kernel<<<56 * BB, 256, 0, stream>>>(feat\
ures, Ag, out);
}

// Round 9
// 56.684 us; speedup vs baseline: 1.8755x; 1.0289x over previous
//
#include <hip/hip_runtime.h>
#include <hip/hip_bf16.h>

#define BB   16
#define EMB  768
#define CIN  64
#define COUT 64
#define HH   112
#define WW   112
#define HID  192
#define TOTAL 36864                 // COUT*CIN*9
#define KSZ  576                    // CIN*9
#define SCOLS 114                   // padded cols (-1..112)
#define CELLH 64                    // bytes per (row,col) cell: 32 ci * 2B (one half)
#define ROWBH (SCOLS * CELLH)       // 7296 B per padded row (half)

typedef short bf16x8 __attribute__((ext_vector_type(8)));
typedef float f32x4  __attribute__((ext_vector_type(4)));
typedef int   i32x4  __attribute__((ext_vector_type(4)));
typedef int   i32x2  __attribute__((ext_vector_type(2)));

static __device__ __forceinline__ unsigned short f2bf(float f) {
    unsigned u = __float_as_uint(f);
    u += 0x7FFF + ((u >> 16) & 1);          // RNE
    return (unsigned short)(u >> 16);
}

static __device__ __forceinline__ bf16x8 pack8(const float* v) {
    bf16x8 r;
    #pragma unroll
    for (int j = 0; j < 8; ++j) r[j] = (short)f2bf(v[j]);
    return r;
}

// ---- K1: h = relu(cls @ W1 + b1).  192 blocks = 16b x 12jg; 256 thr = 16j x 16kq ----
__global__ __launch_bounds__(256) void mlp1_kernel(const float* __restrict__ cls,
                                                   const float* __restrict__ W1,
                                                   const float* __restrict__ b1,
                                                   float* __restrict__ h) {
    __shared__ float xs[EMB];
    __shared__ float red[16][17];
    const int b   = blockIdx.x / 12;
    const int jg  = blockIdx.x - 12 * b;
    const int tid = threadIdx.x;
    for (int i = tid; i < EMB; i += 256) xs[i] = cls[b * EMB + i];
    __syncthreads();
    const int j16 = tid & 15;
    const int kq  = tid >> 4;
    const int j   = jg * 16 + j16;
    float acc = 0.f;
    #pragma unroll
    for (int k = kq * 48; k < kq * 48 + 48; ++k) acc += xs[k] * W1[k * HID + j];
    red[j16][kq] = acc;
    __syncthreads();
    if (tid < 16) {
        float s = b1[jg * 16 + tid];
        #pragma unroll
        for (int q = 0; q < 16; ++q) s += red[tid][q];
        h[b * HID + jg * 16 + tid] = fmaxf(s, 0.f);
    }
}

// ---- K2: MFMA GEMM  params = tanh(h @ W2 + b2) (+ identity at center tap),
//      bf16 out as A[b][p9][co][ci].  M=16(b), K=192, N=36864. ----
__global__ __launch_bounds__(256) void mlp2_kernel(const float* __restrict__ h,
                                                   const float* __restrict__ W2,
                                                   const float* __restrict__ b2,
                                                   unsigned short* __restrict__ Ag) {
    __shared__ float hs[16 * 193];
    const int tid = threadIdx.x;
    for (int i = tid; i < BB * HID; i += 256) {
        const int bb = i / HID;
        hs[bb * 193 + (i - bb * HID)] = h[i];
    }
    __syncthreads();
    const int wave = tid >> 6;
    const int lane = tid & 63;
    const int lg   = lane >> 4;
    const int ln   = lane & 15;
    const int t0   = (blockIdx.x * 4 + wave) * 16;

    bf16x8 a6[6];
    #pragma unroll
    for (int kk = 0; kk < 6; ++kk) {
        float v[8];
        #pragma unroll
        for (int j = 0; j < 8; ++j) v[j] = hs[ln * 193 + kk * 32 + lg * 8 + j];
        a6[kk] = pack8(v);
    }

    f32x4 acc = (f32x4){0.f, 0.f, 0.f, 0.f};
    #pragma unroll
    for (int kk = 0; kk < 6; ++kk) {
        float w[8];
        #pragma unroll
        for (int j = 0; j < 8; ++j)
            w[j] = W2[(size_t)(kk * 32 + lg * 8 + j) * TOTAL + t0 + ln];
        acc = __builtin_amdgcn_mfma_f32_16x16x32_bf16(a6[kk], pack8(w), acc, 0, 0, 0);
    }

    const int t    = t0 + ln;
    const float bias = b2[t];
    const int co  = t / KSZ;
    const int rem = t - co * KSZ;
    const int ci  = rem / 9;
    const int p9  = rem - ci * 9;
    const float idv = (p9 == 4 && co == ci) ? 1.f : 0.f;
    unsigned short* pA = Ag + (size_t)(p9 * 64 + co) * 64 + ci;
    #pragma unroll
    for (int rg = 0; rg < 4; ++rg) {
        const int bi = lg * 4 + rg;
        pA[(size_t)bi * TOTAL] = f2bf(tanhf(acc[rg] + bias) + idv);
    }
}

// -------- K3: conv MFMA implicit GEMM, ci-halved LDS (29 KB) for 4 blocks/CU --------
// Block: 256 thr / 4 waves; wave = (co-half cog, out-row r). 64 co x 2 rows x 112 px.
// LDS per half: 4 rows x 114 cells x 64 B (32 ci); slice sl = (octet ^ (cell&3) ^ row)&3.
// Schedule: stage(h0) | bar | compute(h0) | bar | stage(h1) | bar | compute(h1).
__global__ __launch_bounds__(256, 4) void conv_kernel(const float* __restrict__ feat,
                                                      const unsigned short* __restrict__ Ag,
                                                      float* __restrict__ out) {
    __shared__ __align__(16) char lds[4 * ROWBH];   // 29184 B
    const int tid = threadIdx.x;
    // XCD-chunked swizzle: each XCD owns 112 consecutive logical blocks (= 2 batches)
    const int bid  = (blockIdx.x & 7) * 112 + (blockIdx.x >> 3);
    const int b    = bid / 56;
    const int tile = bid - b * 56;
    const int y0   = tile * 2;

    const int wave = tid >> 6;
    const int lane = tid & 63;
    const int cog  = wave & 1;
    const int r    = wave >> 1;
    const int lg   = lane >> 4;
    const int ln   = lane & 15;

    // staging thread mapping
    const int so = tid >> 6;                        // ci octet within half 0..3
    const int sr = (tid >> 4) & 3;                  // staged row 0..3
    const int sx = tid & 15;                        // 8-px chunk, active < 14
    const int sy = y0 - 1 + sr;
    const bool sact = (sx < 14);
    const bool syv  = sact && ((unsigned)sy < HH);
    char* ldsr = lds + sr * ROWBH;
    const f32x4 z4 = {0.f, 0.f, 0.f, 0.f};

    f32x4 acc[2][7];
    #pragma unroll
    for (int ct = 0; ct < 2; ++ct)
        #pragma unroll
        for (int t = 0; t < 7; ++t) acc[ct][t] = (f32x4){0.f, 0.f, 0.f, 0.f};

    const unsigned short* Ab = Ag + (size_t)b * 9 * 4096;

    // zero x-halo cells (0, 113) for all 4 rows (persist across both halves)
    if (tid < 32) {
        const int zr = tid >> 3, zc = ((tid >> 2) & 1) ? (SCOLS - 1) : 0, zs = tid & 3;
        *(i32x4*)(lds + zr * ROWBH + zc * CELLH + zs * 16) = (i32x4){0, 0, 0, 0};
    }

    #pragma unroll
    for (int h = 0; h < 2; ++h) {
        // ---- stage half h ----
        if (h) __syncthreads();                      // compute(h-1) done before overwrite
        if (sact) {
            const float* fp = feat + (((size_t)b * CIN + h * 32 + so * 8) * HH + sy) * WW + 8 * sx;
            #pragma unroll
            for (int jb = 0; jb < 2; ++jb) {
                f32x4 v[4][2];
                #pragma unroll
                for (int j = 0; j < 4; ++j)
                    #pragma unroll
                    for (int c = 0; c < 2; ++c)
                        v[j][c] = syv ? *(const f32x4*)(fp + (size_t)(jb * 4 + j) * (HH * WW) + 4 * c)
                                      : z4;
                #pragma unroll
                for (int i = 0; i < 8; ++i) {
                    const int cell = 8 * sx + i + 1;
                    const int sl   = (so ^ (cell & 3) ^ sr) & 3;
                    const int c = i >> 2, e = i & 3;
                    const unsigned d0 = (unsigned)f2bf(v[0][c][e]) | ((unsigned)f2bf(v[1][c][e]) << 16);
                    const unsigned d1 = (unsigned)f2bf(v[2][c][e]) | ((unsigned)f2bf(v[3][c][e]) << 16);
                    *(i32x2*)(ldsr + cell * CELLH + sl * 16 + jb * 8) = (i32x2){(int)d0, (int)d1};
                }
            }
        }
        __syncthreads();

        // ---- compute half h ----
        #pragma unroll
        for (int p9 = 0; p9 < 9; ++p9) {
            const int kh = p9 / 3, kw = p9 - 3 * kh;
            const int rs = r + kh;
            const bf16x8 a0 = *(const bf16x8*)(Ab + (size_t)(p9 * 64 + cog * 32 + ln) * 64
                                               + h * 32 + lg * 8);
            const bf16x8 a1 = *(const bf16x8*)(Ab + (size_t)(p9 * 64 + cog * 32 + 16 + ln) * 64
                                               + h * 32 + lg * 8);
            const char* lbase = lds + rs * ROWBH;
            #pragma unroll
            for (int t = 0; t < 7; ++t) {
                const int cell = ln + kw + 16 * t;
                const int sl   = (lg ^ (cell & 3) ^ rs) & 3;
                const bf16x8 bf = *(const bf16x8*)(lbase + cell * CELLH + sl * 16);
                acc[0][t] = __builtin_amdgcn_mfma_f32_16x16x32_bf16(a0, bf, acc[0][t], 0, 0, 0);
                acc[1][t] = __builtin_amdgcn_mfma_f32_16x16x32_bf16(a1, bf, acc[1][t], 0, 0, 0);
            }
        }
    }

    // ---- epilogue: pure stores (residual folded into A) ----
    const int y = y0 + r;
    float* ob = out + (((size_t)b * COUT + cog * 32 + lg * 4) * HH + y) * WW + ln;
    #pragma unroll
    for (int ct = 0; ct < 2; ++ct)
        #pragma unroll
        for (int t = 0; t < 7; ++t)
            #pragma unroll
            for (int rg = 0; rg < 4; ++rg)
                ob[((size_t)(ct * 16 + rg)) * HH * WW + t * 16] = acc[ct][t][rg];
}

extern "C" void kernel_launch(void* const* d_in, const int* in_sizes, int n_in,
                              void* d_out, int out_size, void* d_ws, size_t ws_size,
                              hipStream_t stream) {
    const float* cls      = (const float*)d_in[0];
    const float* features = (const float*)d_in[1];
    const float* W1       = (const float*)d_in[2];
    const float* b1       = (const float*)d_in[3];
    const float* W2       = (const float*)d_in[4];
    const float* b2       = (const float*)d_in[5];
    float* out = (float*)d_out;

    float*          h  = (float*)d_ws;                       // 12 KB
    unsigned short* Ag = (unsigned short*)(h + BB * HID);    // 1.18 MB bf16 A[b][p9][co][ci]

    mlp1_kernel<<<192, 256, 0, stream>>>(cls, W1, b1, h);
    mlp2_kernel<<<TOTAL / 64, 256, 0, stream>>>(h, W2, b2, Ag);
    conv_kernel<<<56 * BB, 256, 0, stream>>>(features, Ag, out);
}